// Round 1
// baseline (1619.288 us; speedup 1.0000x reference)
//
#include <hip/hip_runtime.h>

typedef __bf16 bf16_t;
typedef __bf16 bf16x8 __attribute__((ext_vector_type(8)));
typedef float f32x4 __attribute__((ext_vector_type(4)));

#define MB 512
#define ROWS 112      // pair rows per g-block (7 mtiles of 16)
#define MT 7
#define ST 264        // LDS row stride in bf16 (256 + 8 pad -> 2-way bank alias only)
#define TILES_PER_B 6 // ceil(625/112)

// ---------------- conv (k=3, s=2, p=1) + bias + relu, with input-side BN affine fused ----------------
template <int CIN>
__global__ void conv_bn_relu(const float* __restrict__ in, const float* __restrict__ w,
                             const float* __restrict__ bias,
                             const float* __restrict__ statsIn, const float* __restrict__ gIn,
                             const float* __restrict__ bIn, float invcnt,
                             float* __restrict__ out,
                             int Hin, int Win, int Hout, int Wout, int total)
{
    int idx = blockIdx.x * 256 + threadIdx.x;
    if (idx >= total) return;
    int ow = idx % Wout;
    int t  = idx / Wout;
    int oh = t % Hout;  t /= Hout;
    int co = t % 24;
    int n  = t / 24;

    float sc[CIN], sh[CIN];
#pragma unroll
    for (int ci = 0; ci < CIN; ++ci) {
        if (statsIn) {
            float mean = statsIn[ci * 2] * invcnt;
            float var  = statsIn[ci * 2 + 1] * invcnt - mean * mean;
            float s    = gIn[ci] * rsqrtf(var + 1e-5f);
            sc[ci] = s; sh[ci] = bIn[ci] - mean * s;
        } else { sc[ci] = 1.f; sh[ci] = 0.f; }
    }

    float acc = 0.f;
#pragma unroll
    for (int kh = 0; kh < 3; ++kh) {
        int ih = oh * 2 - 1 + kh;
        if ((unsigned)ih >= (unsigned)Hin) continue;
#pragma unroll
        for (int kw = 0; kw < 3; ++kw) {
            int iw = ow * 2 - 1 + kw;
            if ((unsigned)iw >= (unsigned)Win) continue;
            const float* ip = in + ((n * CIN) * Hin + ih) * Win + iw;
            const float* wp = w + co * CIN * 9 + kh * 3 + kw;
#pragma unroll
            for (int ci = 0; ci < CIN; ++ci) {
                float v = sc[ci] * ip[ci * Hin * Win] + sh[ci];
                acc += v * wp[ci * 9];
            }
        }
    }
    out[idx] = fmaxf(acc + bias[co], 0.f);
}

// ---------------- batch-norm stats: per-channel sum / sumsq ----------------
__global__ void bn_stats(const float* __restrict__ y, float* __restrict__ stats, int HW)
{
    const int C = 24, NSLICE = 16;
    int c  = blockIdx.x % C;
    int sl = blockIdx.x / C;
    float s = 0.f, q = 0.f;
    for (int n = sl * NSLICE; n < sl * NSLICE + NSLICE; ++n) {
        const float* p = y + ((size_t)n * C + c) * HW;
        for (int i = threadIdx.x; i < HW; i += 256) {
            float v = p[i];
            s += v; q += v * v;
        }
    }
#pragma unroll
    for (int off = 1; off < 64; off <<= 1) {
        s += __shfl_xor(s, off);
        q += __shfl_xor(q, off);
    }
    __shared__ float red[8];
    int wv = threadIdx.x >> 6;
    if ((threadIdx.x & 63) == 0) { red[wv] = s; red[4 + wv] = q; }
    __syncthreads();
    if (threadIdx.x == 0) {
        atomicAdd(&stats[c * 2],     red[0] + red[1] + red[2] + red[3]);
        atomicAdd(&stats[c * 2 + 1], red[4] + red[5] + red[6] + red[7]);
    }
}

// ---------------- build bf16 features: xf26 = [BN4(conv4) 24ch, coords 2] ; qst bf16 ----------------
__global__ void build_features(const float* __restrict__ y4, const float* __restrict__ stats4,
                               const float* __restrict__ g4, const float* __restrict__ b4,
                               const float* __restrict__ qst,
                               bf16_t* __restrict__ xf26, bf16_t* __restrict__ qstb)
{
    int idx = blockIdx.x * 256 + threadIdx.x;
    if (idx < MB * 11) qstb[idx] = (bf16_t)qst[idx];
    if (idx >= MB * 25) return;
    int b = idx / 25, p = idx % 25;
    const float invcnt = 1.f / (MB * 25);
#pragma unroll
    for (int ch = 0; ch < 24; ++ch) {
        float mean = stats4[ch * 2] * invcnt;
        float var  = stats4[ch * 2 + 1] * invcnt - mean * mean;
        float s    = g4[ch] * rsqrtf(var + 1e-5f);
        float v    = s * y4[(b * 24 + ch) * 25 + p] + (b4[ch] - mean * s);
        xf26[idx * 26 + ch] = (bf16_t)v;
    }
    // faithful to python true division: (p/5 - 2)/2 , (p%5 - 2)/2
    xf26[idx * 26 + 24] = (bf16_t)((p / 5.0f - 2.0f) * 0.5f);
    xf26[idx * 26 + 25] = (bf16_t)(((float)(p % 5) - 2.0f) * 0.5f);
}

// ---------------- weight prep: bf16 casts (gw1 padded K 63->64), fp32 transposes for f ----------------
__global__ void prep_weights(const float* __restrict__ gw1, const float* __restrict__ gw2,
                             const float* __restrict__ gw3, const float* __restrict__ gw4,
                             const float* __restrict__ fw1, const float* __restrict__ fw2,
                             bf16_t* __restrict__ gw1p, bf16_t* __restrict__ gw2b,
                             bf16_t* __restrict__ gw3b, bf16_t* __restrict__ gw4b,
                             float* __restrict__ fw1T, float* __restrict__ fw2T)
{
    int idx = blockIdx.x * 256 + threadIdx.x;
    if (idx < 16384) {
        int nn = idx >> 6, k = idx & 63;
        gw1p[idx] = (k < 63) ? (bf16_t)gw1[nn * 63 + k] : (bf16_t)0.0f;
        return;
    }
    idx -= 16384;
    if (idx < 65536) { gw2b[idx] = (bf16_t)gw2[idx]; return; }
    idx -= 65536;
    if (idx < 65536) { gw3b[idx] = (bf16_t)gw3[idx]; return; }
    idx -= 65536;
    if (idx < 65536) { gw4b[idx] = (bf16_t)gw4[idx]; return; }
    idx -= 65536;
    if (idx < 65536) { int k = idx >> 8, nn = idx & 255; fw1T[idx] = fw1[nn * 256 + k]; return; }
    idx -= 65536;
    if (idx < 65536) { int k = idx >> 8, nn = idx & 255; fw2T[idx] = fw2[nn * 256 + k]; return; }
}

// ---------------- fused g-MLP over pair rows (MFMA bf16) ----------------
__device__ __forceinline__ void layer_mfma(const bf16_t* hs, const bf16_t* __restrict__ W, int K,
                                           int wid, int l15, int quad, f32x4 acc[MT][4])
{
#pragma unroll
    for (int mt = 0; mt < MT; ++mt)
#pragma unroll
        for (int nt = 0; nt < 4; ++nt) acc[mt][nt] = (f32x4)(0.0f);
    for (int ks = 0; ks < (K >> 5); ++ks) {
        bf16x8 af[MT];
#pragma unroll
        for (int mt = 0; mt < MT; ++mt)
            af[mt] = *(const bf16x8*)(hs + (mt * 16 + l15) * ST + ks * 32 + quad * 8);
#pragma unroll
        for (int nt = 0; nt < 4; ++nt) {
            int n = wid * 64 + nt * 16 + l15;
            bf16x8 bfr = *(const bf16x8*)(W + n * K + ks * 32 + quad * 8);
#pragma unroll
            for (int mt = 0; mt < MT; ++mt)
                acc[mt][nt] = __builtin_amdgcn_mfma_f32_16x16x32_bf16(af[mt], bfr, acc[mt][nt], 0, 0, 0);
        }
    }
}

__device__ __forceinline__ void store_relu(bf16_t* hs, const float* __restrict__ bias,
                                           int wid, int l15, int quad, f32x4 acc[MT][4])
{
#pragma unroll
    for (int nt = 0; nt < 4; ++nt) {
        int col = wid * 64 + nt * 16 + l15;
        float bv = bias[col];
#pragma unroll
        for (int mt = 0; mt < MT; ++mt) {
#pragma unroll
            for (int r = 0; r < 4; ++r) {
                int row = mt * 16 + quad * 4 + r;
                hs[row * ST + col] = (bf16_t)fmaxf(acc[mt][nt][r] + bv, 0.f);
            }
        }
    }
}

__global__ void __launch_bounds__(256, 2)
g_mlp(const bf16_t* __restrict__ xf26, const bf16_t* __restrict__ qstb,
      const bf16_t* __restrict__ W1, const bf16_t* __restrict__ W2,
      const bf16_t* __restrict__ W3, const bf16_t* __restrict__ W4,
      const float* __restrict__ b1, const float* __restrict__ b2,
      const float* __restrict__ b3, const float* __restrict__ b4,
      float* __restrict__ xg)
{
    __shared__ __align__(16) bf16_t hs[ROWS * ST];
    int b    = blockIdx.x / TILES_PER_B;
    int tile = blockIdx.x % TILES_PER_B;
    int tid  = threadIdx.x;

    // stage pair-feature rows [ROWS x 64] into LDS (cols: xf26[b][c] 0..25, xf26[b][a] 26..51, qst 52..62, pad 63)
    {
        int m = tid >> 1, hf = tid & 1;
        if (m < ROWS) {
            int p = tile * ROWS + m;
            bf16_t* dst = hs + m * ST + hf * 32;
            if (p < 625) {
                int a = p / 25, c = p - a * 25;
                const bf16_t* f1 = xf26 + (b * 25 + c) * 26;
                const bf16_t* f2 = xf26 + (b * 25 + a) * 26;
                const bf16_t* f3 = qstb + b * 11;
#pragma unroll
                for (int j = 0; j < 32; ++j) {
                    int col = hf * 32 + j;
                    bf16_t u = (bf16_t)0.0f;
                    if (col < 26) u = f1[col];
                    else if (col < 52) u = f2[col - 26];
                    else if (col < 63) u = f3[col - 52];
                    dst[j] = u;
                }
            } else {
#pragma unroll
                for (int j = 0; j < 32; ++j) dst[j] = (bf16_t)0.0f;
            }
        }
    }
    __syncthreads();

    int wid = tid >> 6, lane = tid & 63, l15 = lane & 15, quad = lane >> 4;
    f32x4 acc[MT][4];

    layer_mfma(hs, W1, 64, wid, l15, quad, acc);
    __syncthreads(); store_relu(hs, b1, wid, l15, quad, acc); __syncthreads();
    layer_mfma(hs, W2, 256, wid, l15, quad, acc);
    __syncthreads(); store_relu(hs, b2, wid, l15, quad, acc); __syncthreads();
    layer_mfma(hs, W3, 256, wid, l15, quad, acc);
    __syncthreads(); store_relu(hs, b3, wid, l15, quad, acc); __syncthreads();
    layer_mfma(hs, W4, 256, wid, l15, quad, acc);

    // epilogue: relu(acc + b4), mask padded rows, sum over rows, atomic into xg
    int nvalid = 625 - tile * ROWS; if (nvalid > ROWS) nvalid = ROWS;
#pragma unroll
    for (int nt = 0; nt < 4; ++nt) {
        int col = wid * 64 + nt * 16 + l15;
        float bv = b4[col];
        float s = 0.f;
#pragma unroll
        for (int mt = 0; mt < MT; ++mt) {
#pragma unroll
            for (int r = 0; r < 4; ++r) {
                int row = mt * 16 + quad * 4 + r;
                float v = fmaxf(acc[mt][nt][r] + bv, 0.f);
                s += (row < nvalid) ? v : 0.f;
            }
        }
        s += __shfl_xor(s, 16);
        s += __shfl_xor(s, 32);
        if (quad == 0) atomicAdd(&xg[b * 256 + col], s);
    }
}

// ---------------- f-MLP (fp32) + log_softmax, one block per batch element ----------------
__global__ void f_mlp(const float* __restrict__ xg, const float* __restrict__ fw1T, const float* __restrict__ fb1,
                      const float* __restrict__ fw2T, const float* __restrict__ fb2,
                      const float* __restrict__ fw3, const float* __restrict__ fb3,
                      float* __restrict__ out)
{
    __shared__ float xa[256], xb[256], lg[10];
    int b = blockIdx.x, t = threadIdx.x;
    xa[t] = xg[b * 256 + t];
    __syncthreads();
    float a = fb1[t];
    for (int k = 0; k < 256; ++k) a += fw1T[k * 256 + t] * xa[k];
    xb[t] = fmaxf(a, 0.f);
    __syncthreads();
    a = fb2[t];
    for (int k = 0; k < 256; ++k) a += fw2T[k * 256 + t] * xb[k];
    xa[t] = fmaxf(a, 0.f);
    __syncthreads();
    if (t < 10) {
        float s = fb3[t];
        for (int k = 0; k < 256; ++k) s += fw3[t * 256 + k] * xa[k];
        lg[t] = s;
    }
    __syncthreads();
    if (t == 0) {
        float m = lg[0];
        for (int i = 1; i < 10; ++i) m = fmaxf(m, lg[i]);
        float s = 0.f;
        for (int i = 0; i < 10; ++i) s += expf(lg[i] - m);
        float ls = m + logf(s);
        for (int i = 0; i < 10; ++i) out[b * 10 + i] = lg[i] - ls;
    }
}

// ---------------- launch ----------------
extern "C" void kernel_launch(void* const* d_in, const int* in_sizes, int n_in,
                              void* d_out, int out_size, void* d_ws, size_t ws_size,
                              hipStream_t stream)
{
    (void)in_sizes; (void)n_in; (void)out_size; (void)ws_size;
    const float* img  = (const float*)d_in[0];
    const float* qst  = (const float*)d_in[1];
    const float* c1w  = (const float*)d_in[2];
    const float* c1b  = (const float*)d_in[3];
    const float* bn1g = (const float*)d_in[4];
    const float* bn1b = (const float*)d_in[5];
    const float* c2w  = (const float*)d_in[6];
    const float* c2b  = (const float*)d_in[7];
    const float* bn2g = (const float*)d_in[8];
    const float* bn2b = (const float*)d_in[9];
    const float* c3w  = (const float*)d_in[10];
    const float* c3b  = (const float*)d_in[11];
    const float* bn3g = (const float*)d_in[12];
    const float* bn3b = (const float*)d_in[13];
    const float* c4w  = (const float*)d_in[14];
    const float* c4b  = (const float*)d_in[15];
    const float* bn4g = (const float*)d_in[16];
    const float* bn4b = (const float*)d_in[17];
    const float* gw1  = (const float*)d_in[18];
    const float* gb1  = (const float*)d_in[19];
    const float* gw2  = (const float*)d_in[20];
    const float* gb2  = (const float*)d_in[21];
    const float* gw3  = (const float*)d_in[22];
    const float* gb3  = (const float*)d_in[23];
    const float* gw4  = (const float*)d_in[24];
    const float* gb4  = (const float*)d_in[25];
    const float* fw1  = (const float*)d_in[26];
    const float* fb1  = (const float*)d_in[27];
    const float* fw2  = (const float*)d_in[28];
    const float* fb2  = (const float*)d_in[29];
    const float* fw3  = (const float*)d_in[30];
    const float* fb3  = (const float*)d_in[31];

    const int Y1 = 512 * 24 * 38 * 38;   // 17,744,896
    const int Y2 = 512 * 24 * 19 * 19;   //  4,435,968
    const int Y3 = 512 * 24 * 10 * 10;   //  1,228,800
    const int Y4 = 512 * 24 * 5 * 5;     //    307,200

    float* fp = (float*)d_ws;
    float* y1    = fp;  fp += Y1;
    float* y2    = fp;  fp += Y2;
    float* y3    = fp;  fp += Y3;
    float* y4    = fp;  fp += Y4;
    float* stats = fp;  fp += 192;       // [4 layers][24 ch][sum, sumsq]
    float* xg    = fp;  fp += 512 * 256;
    float* fw1T  = fp;  fp += 65536;
    float* fw2T  = fp;  fp += 65536;
    bf16_t* bp   = (bf16_t*)fp;
    bf16_t* xf26 = bp;  bp += 512 * 25 * 26;
    bf16_t* qstb = bp;  bp += 512 * 11;
    bf16_t* gw1p = bp;  bp += 256 * 64;
    bf16_t* gw2b = bp;  bp += 65536;
    bf16_t* gw3b = bp;  bp += 65536;
    bf16_t* gw4b = bp;  bp += 65536;

    hipMemsetAsync(stats, 0, 192 * sizeof(float), stream);
    hipMemsetAsync(xg, 0, 512 * 256 * sizeof(float), stream);

    prep_weights<<<1344, 256, 0, stream>>>(gw1, gw2, gw3, gw4, fw1, fw2,
                                           gw1p, gw2b, gw3b, gw4b, fw1T, fw2T);

    conv_bn_relu<3><<<Y1 / 256, 256, 0, stream>>>(img, c1w, c1b, nullptr, nullptr, nullptr, 0.f,
                                                  y1, 75, 75, 38, 38, Y1);
    bn_stats<<<24 * 32, 256, 0, stream>>>(y1, stats + 0, 38 * 38);

    conv_bn_relu<24><<<Y2 / 256, 256, 0, stream>>>(y1, c2w, c2b, stats + 0, bn1g, bn1b,
                                                   1.f / (512.f * 1444.f), y2, 38, 38, 19, 19, Y2);
    bn_stats<<<24 * 32, 256, 0, stream>>>(y2, stats + 48, 19 * 19);

    conv_bn_relu<24><<<Y3 / 256, 256, 0, stream>>>(y2, c3w, c3b, stats + 48, bn2g, bn2b,
                                                   1.f / (512.f * 361.f), y3, 19, 19, 10, 10, Y3);
    bn_stats<<<24 * 32, 256, 0, stream>>>(y3, stats + 96, 10 * 10);

    conv_bn_relu<24><<<Y4 / 256, 256, 0, stream>>>(y3, c4w, c4b, stats + 96, bn3g, bn3b,
                                                   1.f / (512.f * 100.f), y4, 10, 10, 5, 5, Y4);
    bn_stats<<<24 * 32, 256, 0, stream>>>(y4, stats + 144, 5 * 5);

    build_features<<<50, 256, 0, stream>>>(y4, stats + 144, bn4g, bn4b, qst, xf26, qstb);

    g_mlp<<<512 * TILES_PER_B, 256, 0, stream>>>(xf26, qstb, gw1p, gw2b, gw3b, gw4b,
                                                 gb1, gb2, gb3, gb4, xg);

    f_mlp<<<512, 256, 0, stream>>>(xg, fw1T, fb1, fw2T, fb2, fw3, fb3, (float*)d_out);
}

// Round 2
// 1509.561 us; speedup vs baseline: 1.0727x; 1.0727x over previous
//
#include <hip/hip_runtime.h>

typedef __bf16 bf16_t;
typedef __bf16 bf16x8 __attribute__((ext_vector_type(8)));
typedef float f32x4 __attribute__((ext_vector_type(4)));

#define MB 512
#define ROWS 112      // pair rows per g-block (7 mtiles of 16)
#define MT 7
#define ST 264        // LDS row stride in bf16 (256 + 8 pad -> 2-way bank alias only)
#define TILES_PER_B 6 // ceil(625/112)

// ================= conv1: CIN=3, 75x75 -> 38x38, LDS-tiled, fused bias/relu + bn-stats =================
// block = (image n, half-tile of 19 output rows). LDS: zero-padded input [3][39][77] + weights [27][24].
__global__ __launch_bounds__(256, 2) void conv1_bn(const float* __restrict__ img,
                                                   const float* __restrict__ w,
                                                   const float* __restrict__ bias,
                                                   float* __restrict__ out,
                                                   float* __restrict__ statsOut)
{
    __shared__ float in_s[3 * 39 * 77];   // 36,036 B
    __shared__ float w_s[27 * 24];        //  2,592 B
    int bid = blockIdx.x;
    int n = bid >> 1, tile = bid & 1;
    int oh0 = tile * 19;
    int tid = threadIdx.x;

    for (int idx = tid; idx < 648; idx += 256) {
        int k = idx / 24, co = idx - k * 24;
        w_s[idx] = w[co * 27 + k];
    }
    for (int idx = tid; idx < 3 * 39 * 77; idx += 256) {
        int ci = idx / (39 * 77);
        int rem = idx - ci * (39 * 77);
        int r = rem / 77, c = rem - r * 77;
        int ih = 2 * oh0 - 1 + r, iw = c - 1;
        float v = 0.f;
        if ((unsigned)ih < 75u && (unsigned)iw < 75u)
            v = img[((n * 3 + ci) * 75 + ih) * 75 + iw];
        in_s[idx] = v;
    }
    __syncthreads();

    int cg = tid >> 6, lane = tid & 63, co0 = cg * 6;
    int off[12];
    bool pv[12];
#pragma unroll
    for (int j = 0; j < 12; ++j) {
        int p = lane + j * 64;
        pv[j] = p < 722;
        int pc = pv[j] ? p : 0;
        int r0 = pc / 38, c0 = pc - r0 * 38;
        off[j] = (r0 * 2) * 77 + c0 * 2;
    }
    float acc[6][12];
#pragma unroll
    for (int c = 0; c < 6; ++c)
#pragma unroll
        for (int j = 0; j < 12; ++j) acc[c][j] = 0.f;

#pragma unroll 1
    for (int ci = 0; ci < 3; ++ci) {
        const float* ip = in_s + ci * (39 * 77);
        const float* wp = w_s + ci * 9 * 24 + co0;
#pragma unroll
        for (int kh = 0; kh < 3; ++kh) {
#pragma unroll
            for (int kw = 0; kw < 3; ++kw) {
                float iv[12];
#pragma unroll
                for (int j = 0; j < 12; ++j) iv[j] = ip[off[j] + kh * 77 + kw];
                const float* wr = wp + (kh * 3 + kw) * 24;
                float2 w01 = *(const float2*)(wr);
                float2 w23 = *(const float2*)(wr + 2);
                float2 w45 = *(const float2*)(wr + 4);
#pragma unroll
                for (int j = 0; j < 12; ++j) {
                    acc[0][j] = fmaf(iv[j], w01.x, acc[0][j]);
                    acc[1][j] = fmaf(iv[j], w01.y, acc[1][j]);
                    acc[2][j] = fmaf(iv[j], w23.x, acc[2][j]);
                    acc[3][j] = fmaf(iv[j], w23.y, acc[3][j]);
                    acc[4][j] = fmaf(iv[j], w45.x, acc[4][j]);
                    acc[5][j] = fmaf(iv[j], w45.y, acc[5][j]);
                }
            }
        }
    }

    float sst[6], sq[6];
#pragma unroll
    for (int c = 0; c < 6; ++c) { sst[c] = 0.f; sq[c] = 0.f; }
#pragma unroll
    for (int c = 0; c < 6; ++c) {
        float bv = bias[co0 + c];
#pragma unroll
        for (int j = 0; j < 12; ++j) {
            if (pv[j]) {
                int p = lane + j * 64;
                int r = p / 38, q = p - r * 38;
                float v = fmaxf(acc[c][j] + bv, 0.f);
                out[((n * 24 + co0 + c) * 38 + oh0 + r) * 38 + q] = v;
                sst[c] += v; sq[c] += v * v;
            }
        }
    }
#pragma unroll
    for (int o = 1; o < 64; o <<= 1) {
#pragma unroll
        for (int c = 0; c < 6; ++c) {
            sst[c] += __shfl_xor(sst[c], o);
            sq[c]  += __shfl_xor(sq[c], o);
        }
    }
    if (lane == 0) {
#pragma unroll
        for (int c = 0; c < 6; ++c) {
            atomicAdd(&statsOut[(co0 + c) * 2],     sst[c]);
            atomicAdd(&statsOut[(co0 + c) * 2 + 1], sq[c]);
        }
    }
}

// ================= conv2/3/4: CIN=24, LDS-tiled, input-side BN affine applied at stage time =================
template <int HIN, int WIN, int HOUT, int WOUT, int OHT, int NP>
__global__ __launch_bounds__(256, 2) void conv24_bn(const float* __restrict__ in,
                                                    const float* __restrict__ w,
                                                    const float* __restrict__ bias,
                                                    const float* __restrict__ statsIn,
                                                    const float* __restrict__ gIn,
                                                    const float* __restrict__ bIn, float invcntIn,
                                                    float* __restrict__ out,
                                                    float* __restrict__ statsOut, int tilesPerImg)
{
    constexpr int IR = 2 * OHT + 1;
    constexpr int ICW = 2 * WOUT + 1;
    __shared__ float in_s[24 * IR * ICW];
    __shared__ float w_s[216 * 24];
    __shared__ float aff[48];

    int bid = blockIdx.x;
    int n = bid / tilesPerImg, tile = bid - n * tilesPerImg;
    int oh0 = tile * OHT;
    int tid = threadIdx.x;

    if (tid < 24) {
        float mean = statsIn[tid * 2] * invcntIn;
        float var  = statsIn[tid * 2 + 1] * invcntIn - mean * mean;
        float s    = gIn[tid] * rsqrtf(var + 1e-5f);
        aff[tid * 2] = s;
        aff[tid * 2 + 1] = bIn[tid] - mean * s;
    }
    for (int idx = tid; idx < 5184; idx += 256) {
        int k = idx / 24, co = idx - k * 24;
        w_s[idx] = w[co * 216 + k];
    }
    __syncthreads();  // aff ready
    for (int idx = tid; idx < 24 * IR * ICW; idx += 256) {
        int ci = idx / (IR * ICW);
        int rem = idx - ci * (IR * ICW);
        int r = rem / ICW, c = rem - r * ICW;
        int ih = 2 * oh0 - 1 + r, iw = c - 1;
        float v = 0.f;
        if ((unsigned)ih < (unsigned)HIN && (unsigned)iw < (unsigned)WIN)
            v = aff[ci * 2] * in[((n * 24 + ci) * HIN + ih) * WIN + iw] + aff[ci * 2 + 1];
        in_s[idx] = v;
    }
    __syncthreads();

    int cg = tid >> 6, lane = tid & 63, co0 = cg * 6;
    int nvr = HOUT - oh0; if (nvr > OHT) nvr = OHT;
    int nposv = nvr * WOUT;
    int off[NP];
    bool pv[NP];
#pragma unroll
    for (int j = 0; j < NP; ++j) {
        int p = lane + j * 64;
        pv[j] = p < nposv;
        int pc = pv[j] ? p : 0;
        int r0 = pc / WOUT, c0 = pc - r0 * WOUT;
        off[j] = (r0 * 2) * ICW + c0 * 2;
    }
    float acc[6][NP];
#pragma unroll
    for (int c = 0; c < 6; ++c)
#pragma unroll
        for (int j = 0; j < NP; ++j) acc[c][j] = 0.f;

#pragma unroll 1
    for (int ci = 0; ci < 24; ++ci) {
        const float* ip = in_s + ci * (IR * ICW);
        const float* wp = w_s + ci * 9 * 24 + co0;
#pragma unroll
        for (int kh = 0; kh < 3; ++kh) {
#pragma unroll
            for (int kw = 0; kw < 3; ++kw) {
                float iv[NP];
#pragma unroll
                for (int j = 0; j < NP; ++j) iv[j] = ip[off[j] + kh * ICW + kw];
                const float* wr = wp + (kh * 3 + kw) * 24;
                float2 w01 = *(const float2*)(wr);
                float2 w23 = *(const float2*)(wr + 2);
                float2 w45 = *(const float2*)(wr + 4);
#pragma unroll
                for (int j = 0; j < NP; ++j) {
                    acc[0][j] = fmaf(iv[j], w01.x, acc[0][j]);
                    acc[1][j] = fmaf(iv[j], w01.y, acc[1][j]);
                    acc[2][j] = fmaf(iv[j], w23.x, acc[2][j]);
                    acc[3][j] = fmaf(iv[j], w23.y, acc[3][j]);
                    acc[4][j] = fmaf(iv[j], w45.x, acc[4][j]);
                    acc[5][j] = fmaf(iv[j], w45.y, acc[5][j]);
                }
            }
        }
    }

    float sst[6], sq[6];
#pragma unroll
    for (int c = 0; c < 6; ++c) { sst[c] = 0.f; sq[c] = 0.f; }
#pragma unroll
    for (int c = 0; c < 6; ++c) {
        float bv = bias[co0 + c];
#pragma unroll
        for (int j = 0; j < NP; ++j) {
            if (pv[j]) {
                int p = lane + j * 64;
                int r = p / WOUT, q = p - r * WOUT;
                float v = fmaxf(acc[c][j] + bv, 0.f);
                out[((n * 24 + co0 + c) * HOUT + oh0 + r) * WOUT + q] = v;
                sst[c] += v; sq[c] += v * v;
            }
        }
    }
#pragma unroll
    for (int o = 1; o < 64; o <<= 1) {
#pragma unroll
        for (int c = 0; c < 6; ++c) {
            sst[c] += __shfl_xor(sst[c], o);
            sq[c]  += __shfl_xor(sq[c], o);
        }
    }
    if (lane == 0) {
#pragma unroll
        for (int c = 0; c < 6; ++c) {
            atomicAdd(&statsOut[(co0 + c) * 2],     sst[c]);
            atomicAdd(&statsOut[(co0 + c) * 2 + 1], sq[c]);
        }
    }
}

// ---------------- build bf16 features: xf26 = [BN4(conv4) 24ch, coords 2] ; qst bf16 ----------------
__global__ void build_features(const float* __restrict__ y4, const float* __restrict__ stats4,
                               const float* __restrict__ g4, const float* __restrict__ b4,
                               const float* __restrict__ qst,
                               bf16_t* __restrict__ xf26, bf16_t* __restrict__ qstb)
{
    int idx = blockIdx.x * 256 + threadIdx.x;
    if (idx < MB * 11) qstb[idx] = (bf16_t)qst[idx];
    if (idx >= MB * 25) return;
    int b = idx / 25, p = idx % 25;
    const float invcnt = 1.f / (MB * 25);
#pragma unroll
    for (int ch = 0; ch < 24; ++ch) {
        float mean = stats4[ch * 2] * invcnt;
        float var  = stats4[ch * 2 + 1] * invcnt - mean * mean;
        float s    = g4[ch] * rsqrtf(var + 1e-5f);
        float v    = s * y4[(b * 24 + ch) * 25 + p] + (b4[ch] - mean * s);
        xf26[idx * 26 + ch] = (bf16_t)v;
    }
    xf26[idx * 26 + 24] = (bf16_t)((p / 5.0f - 2.0f) * 0.5f);
    xf26[idx * 26 + 25] = (bf16_t)(((float)(p % 5) - 2.0f) * 0.5f);
}

// ---------------- weight prep: bf16 casts (gw1 padded K 63->64), fp32 transposes for f ----------------
__global__ void prep_weights(const float* __restrict__ gw1, const float* __restrict__ gw2,
                             const float* __restrict__ gw3, const float* __restrict__ gw4,
                             const float* __restrict__ fw1, const float* __restrict__ fw2,
                             bf16_t* __restrict__ gw1p, bf16_t* __restrict__ gw2b,
                             bf16_t* __restrict__ gw3b, bf16_t* __restrict__ gw4b,
                             float* __restrict__ fw1T, float* __restrict__ fw2T)
{
    int idx = blockIdx.x * 256 + threadIdx.x;
    if (idx < 16384) {
        int nn = idx >> 6, k = idx & 63;
        gw1p[idx] = (k < 63) ? (bf16_t)gw1[nn * 63 + k] : (bf16_t)0.0f;
        return;
    }
    idx -= 16384;
    if (idx < 65536) { gw2b[idx] = (bf16_t)gw2[idx]; return; }
    idx -= 65536;
    if (idx < 65536) { gw3b[idx] = (bf16_t)gw3[idx]; return; }
    idx -= 65536;
    if (idx < 65536) { gw4b[idx] = (bf16_t)gw4[idx]; return; }
    idx -= 65536;
    if (idx < 65536) { int k = idx >> 8, nn = idx & 255; fw1T[idx] = fw1[nn * 256 + k]; return; }
    idx -= 65536;
    if (idx < 65536) { int k = idx >> 8, nn = idx & 255; fw2T[idx] = fw2[nn * 256 + k]; return; }
}

// ---------------- fused g-MLP over pair rows (MFMA bf16) ----------------
__device__ __forceinline__ void layer_mfma(const bf16_t* hs, const bf16_t* __restrict__ W, int K,
                                           int wid, int l15, int quad, f32x4 acc[MT][4])
{
#pragma unroll
    for (int mt = 0; mt < MT; ++mt)
#pragma unroll
        for (int nt = 0; nt < 4; ++nt) acc[mt][nt] = (f32x4)(0.0f);
    for (int ks = 0; ks < (K >> 5); ++ks) {
        bf16x8 af[MT];
#pragma unroll
        for (int mt = 0; mt < MT; ++mt)
            af[mt] = *(const bf16x8*)(hs + (mt * 16 + l15) * ST + ks * 32 + quad * 8);
#pragma unroll
        for (int nt = 0; nt < 4; ++nt) {
            int n = wid * 64 + nt * 16 + l15;
            bf16x8 bfr = *(const bf16x8*)(W + n * K + ks * 32 + quad * 8);
#pragma unroll
            for (int mt = 0; mt < MT; ++mt)
                acc[mt][nt] = __builtin_amdgcn_mfma_f32_16x16x32_bf16(af[mt], bfr, acc[mt][nt], 0, 0, 0);
        }
    }
}

__device__ __forceinline__ void store_relu(bf16_t* hs, const float* __restrict__ bias,
                                           int wid, int l15, int quad, f32x4 acc[MT][4])
{
#pragma unroll
    for (int nt = 0; nt < 4; ++nt) {
        int col = wid * 64 + nt * 16 + l15;
        float bv = bias[col];
#pragma unroll
        for (int mt = 0; mt < MT; ++mt) {
#pragma unroll
            for (int r = 0; r < 4; ++r) {
                int row = mt * 16 + quad * 4 + r;
                hs[row * ST + col] = (bf16_t)fmaxf(acc[mt][nt][r] + bv, 0.f);
            }
        }
    }
}

__global__ void __launch_bounds__(256, 2)
g_mlp(const bf16_t* __restrict__ xf26, const bf16_t* __restrict__ qstb,
      const bf16_t* __restrict__ W1, const bf16_t* __restrict__ W2,
      const bf16_t* __restrict__ W3, const bf16_t* __restrict__ W4,
      const float* __restrict__ b1, const float* __restrict__ b2,
      const float* __restrict__ b3, const float* __restrict__ b4,
      float* __restrict__ xg)
{
    __shared__ __align__(16) bf16_t hs[ROWS * ST];
    int b    = blockIdx.x / TILES_PER_B;
    int tile = blockIdx.x % TILES_PER_B;
    int tid  = threadIdx.x;

    {
        int m = tid >> 1, hf = tid & 1;
        if (m < ROWS) {
            int p = tile * ROWS + m;
            bf16_t* dst = hs + m * ST + hf * 32;
            if (p < 625) {
                int a = p / 25, c = p - a * 25;
                const bf16_t* f1 = xf26 + (b * 25 + c) * 26;
                const bf16_t* f2 = xf26 + (b * 25 + a) * 26;
                const bf16_t* f3 = qstb + b * 11;
#pragma unroll
                for (int j = 0; j < 32; ++j) {
                    int col = hf * 32 + j;
                    bf16_t u = (bf16_t)0.0f;
                    if (col < 26) u = f1[col];
                    else if (col < 52) u = f2[col - 26];
                    else if (col < 63) u = f3[col - 52];
                    dst[j] = u;
                }
            } else {
#pragma unroll
                for (int j = 0; j < 32; ++j) dst[j] = (bf16_t)0.0f;
            }
        }
    }
    __syncthreads();

    int wid = tid >> 6, lane = tid & 63, l15 = lane & 15, quad = lane >> 4;
    f32x4 acc[MT][4];

    layer_mfma(hs, W1, 64, wid, l15, quad, acc);
    __syncthreads(); store_relu(hs, b1, wid, l15, quad, acc); __syncthreads();
    layer_mfma(hs, W2, 256, wid, l15, quad, acc);
    __syncthreads(); store_relu(hs, b2, wid, l15, quad, acc); __syncthreads();
    layer_mfma(hs, W3, 256, wid, l15, quad, acc);
    __syncthreads(); store_relu(hs, b3, wid, l15, quad, acc); __syncthreads();
    layer_mfma(hs, W4, 256, wid, l15, quad, acc);

    int nvalid = 625 - tile * ROWS; if (nvalid > ROWS) nvalid = ROWS;
#pragma unroll
    for (int nt = 0; nt < 4; ++nt) {
        int col = wid * 64 + nt * 16 + l15;
        float bv = b4[col];
        float s = 0.f;
#pragma unroll
        for (int mt = 0; mt < MT; ++mt) {
#pragma unroll
            for (int r = 0; r < 4; ++r) {
                int row = mt * 16 + quad * 4 + r;
                float v = fmaxf(acc[mt][nt][r] + bv, 0.f);
                s += (row < nvalid) ? v : 0.f;
            }
        }
        s += __shfl_xor(s, 16);
        s += __shfl_xor(s, 32);
        if (quad == 0) atomicAdd(&xg[b * 256 + col], s);
    }
}

// ---------------- f-MLP (fp32) + log_softmax, one block per batch element ----------------
__global__ void f_mlp(const float* __restrict__ xg, const float* __restrict__ fw1T, const float* __restrict__ fb1,
                      const float* __restrict__ fw2T, const float* __restrict__ fb2,
                      const float* __restrict__ fw3, const float* __restrict__ fb3,
                      float* __restrict__ out)
{
    __shared__ float xa[256], xb[256], lg[10];
    int b = blockIdx.x, t = threadIdx.x;
    xa[t] = xg[b * 256 + t];
    __syncthreads();
    float a = fb1[t];
    for (int k = 0; k < 256; ++k) a += fw1T[k * 256 + t] * xa[k];
    xb[t] = fmaxf(a, 0.f);
    __syncthreads();
    a = fb2[t];
    for (int k = 0; k < 256; ++k) a += fw2T[k * 256 + t] * xb[k];
    xa[t] = fmaxf(a, 0.f);
    __syncthreads();
    if (t < 10) {
        float s = fb3[t];
        for (int k = 0; k < 256; ++k) s += fw3[t * 256 + k] * xa[k];
        lg[t] = s;
    }
    __syncthreads();
    if (t == 0) {
        float m = lg[0];
        for (int i = 1; i < 10; ++i) m = fmaxf(m, lg[i]);
        float s = 0.f;
        for (int i = 0; i < 10; ++i) s += expf(lg[i] - m);
        float ls = m + logf(s);
        for (int i = 0; i < 10; ++i) out[b * 10 + i] = lg[i] - ls;
    }
}

// ---------------- launch ----------------
extern "C" void kernel_launch(void* const* d_in, const int* in_sizes, int n_in,
                              void* d_out, int out_size, void* d_ws, size_t ws_size,
                              hipStream_t stream)
{
    (void)in_sizes; (void)n_in; (void)out_size; (void)ws_size;
    const float* img  = (const float*)d_in[0];
    const float* qst  = (const float*)d_in[1];
    const float* c1w  = (const float*)d_in[2];
    const float* c1b  = (const float*)d_in[3];
    const float* bn1g = (const float*)d_in[4];
    const float* bn1b = (const float*)d_in[5];
    const float* c2w  = (const float*)d_in[6];
    const float* c2b  = (const float*)d_in[7];
    const float* bn2g = (const float*)d_in[8];
    const float* bn2b = (const float*)d_in[9];
    const float* c3w  = (const float*)d_in[10];
    const float* c3b  = (const float*)d_in[11];
    const float* bn3g = (const float*)d_in[12];
    const float* bn3b = (const float*)d_in[13];
    const float* c4w  = (const float*)d_in[14];
    const float* c4b  = (const float*)d_in[15];
    const float* bn4g = (const float*)d_in[16];
    const float* bn4b = (const float*)d_in[17];
    const float* gw1  = (const float*)d_in[18];
    const float* gb1  = (const float*)d_in[19];
    const float* gw2  = (const float*)d_in[20];
    const float* gb2  = (const float*)d_in[21];
    const float* gw3  = (const float*)d_in[22];
    const float* gb3  = (const float*)d_in[23];
    const float* gw4  = (const float*)d_in[24];
    const float* gb4  = (const float*)d_in[25];
    const float* fw1  = (const float*)d_in[26];
    const float* fb1  = (const float*)d_in[27];
    const float* fw2  = (const float*)d_in[28];
    const float* fb2  = (const float*)d_in[29];
    const float* fw3  = (const float*)d_in[30];
    const float* fb3  = (const float*)d_in[31];

    const int Y1 = 512 * 24 * 38 * 38;
    const int Y2 = 512 * 24 * 19 * 19;
    const int Y3 = 512 * 24 * 10 * 10;
    const int Y4 = 512 * 24 * 5 * 5;

    float* fp = (float*)d_ws;
    float* y1    = fp;  fp += Y1;
    float* y2    = fp;  fp += Y2;
    float* y3    = fp;  fp += Y3;
    float* y4    = fp;  fp += Y4;
    float* stats = fp;  fp += 192;       // [4 layers][24 ch][sum, sumsq]
    float* xg    = fp;  fp += 512 * 256;
    float* fw1T  = fp;  fp += 65536;
    float* fw2T  = fp;  fp += 65536;
    bf16_t* bp   = (bf16_t*)fp;
    bf16_t* xf26 = bp;  bp += 512 * 25 * 26;
    bf16_t* qstb = bp;  bp += 512 * 11;
    bf16_t* gw1p = bp;  bp += 256 * 64;
    bf16_t* gw2b = bp;  bp += 65536;
    bf16_t* gw3b = bp;  bp += 65536;
    bf16_t* gw4b = bp;  bp += 65536;

    hipMemsetAsync(stats, 0, 192 * sizeof(float), stream);
    hipMemsetAsync(xg, 0, 512 * 256 * sizeof(float), stream);

    prep_weights<<<1344, 256, 0, stream>>>(gw1, gw2, gw3, gw4, fw1, fw2,
                                           gw1p, gw2b, gw3b, gw4b, fw1T, fw2T);

    // conv1: 512 images x 2 row-tiles
    conv1_bn<<<1024, 256, 0, stream>>>(img, c1w, c1b, y1, stats + 0);

    // conv2: 38x38 -> 19x19, 4 row-tiles of 5
    conv24_bn<38, 38, 19, 19, 5, 2><<<2048, 256, 0, stream>>>(
        y1, c2w, c2b, stats + 0, bn1g, bn1b, 1.f / (512.f * 1444.f),
        y2, stats + 48, 4);

    // conv3: 19x19 -> 10x10, single tile
    conv24_bn<19, 19, 10, 10, 10, 2><<<512, 256, 0, stream>>>(
        y2, c3w, c3b, stats + 48, bn2g, bn2b, 1.f / (512.f * 361.f),
        y3, stats + 96, 1);

    // conv4: 10x10 -> 5x5, single tile
    conv24_bn<10, 10, 5, 5, 5, 1><<<512, 256, 0, stream>>>(
        y3, c4w, c4b, stats + 96, bn3g, bn3b, 1.f / (512.f * 100.f),
        y4, stats + 144, 1);

    build_features<<<50, 256, 0, stream>>>(y4, stats + 144, bn4g, bn4b, qst, xf26, qstb);

    g_mlp<<<512 * TILES_PER_B, 256, 0, stream>>>(xf26, qstb, gw1p, gw2b, gw3b, gw4b,
                                                 gb1, gb2, gb3, gb4, xg);

    f_mlp<<<512, 256, 0, stream>>>(xg, fw1T, fb1, fw2T, fb2, fw3, fb3, (float*)d_out);
}

// Round 3
// 654.965 us; speedup vs baseline: 2.4723x; 2.3048x over previous
//
#include <hip/hip_runtime.h>

typedef __bf16 bf16_t;
typedef __bf16 bf16x8 __attribute__((ext_vector_type(8)));
typedef float f32x4 __attribute__((ext_vector_type(4)));

#define MB 512
#define ROWS 112      // pair rows per g-block (7 mtiles of 16)
#define MT 7
#define ST 264        // LDS row stride in bf16 (256 + 8 pad -> 2-way bank alias only)
#define TILES_PER_B 6 // ceil(625/112)

// ================= conv1: CIN=3, 75x75 -> 38x38, LDS input tile, weights via L1 (wT [27][24]) ============
__global__ __launch_bounds__(256, 2) void conv1_bn(const float* __restrict__ img,
                                                   const float* __restrict__ wT,
                                                   const float* __restrict__ bias,
                                                   float* __restrict__ out,
                                                   float* __restrict__ statsOut)
{
    __shared__ float in_s[3 * 39 * 77];   // 36,036 B
    __shared__ float red[48];
    int bid = blockIdx.x;
    int n = bid >> 1, tile = bid & 1;
    int oh0 = tile * 19;
    int tid = threadIdx.x;

    for (int idx = tid; idx < 3 * 39 * 77; idx += 256) {
        int ci = idx / (39 * 77);
        int rem = idx - ci * (39 * 77);
        int r = rem / 77, c = rem - r * 77;
        int ih = 2 * oh0 - 1 + r, iw = c - 1;
        float v = 0.f;
        if ((unsigned)ih < 75u && (unsigned)iw < 75u)
            v = img[((n * 3 + ci) * 75 + ih) * 75 + iw];
        in_s[idx] = v;
    }
    __syncthreads();

    int cg = tid >> 6, lane = tid & 63, co0 = cg * 6;
    int off[12];
    bool pv[12];
#pragma unroll
    for (int j = 0; j < 12; ++j) {
        int p = lane + j * 64;
        pv[j] = p < 722;
        int pc = pv[j] ? p : 0;
        int r0 = pc / 38, c0 = pc - r0 * 38;
        off[j] = (r0 * 2) * 77 + c0 * 2;
    }
    float acc[6][12];
#pragma unroll
    for (int c = 0; c < 6; ++c)
#pragma unroll
        for (int j = 0; j < 12; ++j) acc[c][j] = 0.f;

#pragma unroll 1
    for (int ci = 0; ci < 3; ++ci) {
        const float* ip = in_s + ci * (39 * 77);
        const float* wp = wT + ci * 9 * 24 + co0;
#pragma unroll
        for (int kh = 0; kh < 3; ++kh) {
#pragma unroll
            for (int kw = 0; kw < 3; ++kw) {
                float iv[12];
#pragma unroll
                for (int j = 0; j < 12; ++j) iv[j] = ip[off[j] + kh * 77 + kw];
                const float* wr = wp + (kh * 3 + kw) * 24;
                float2 w01 = *(const float2*)(wr);
                float2 w23 = *(const float2*)(wr + 2);
                float2 w45 = *(const float2*)(wr + 4);
#pragma unroll
                for (int j = 0; j < 12; ++j) {
                    acc[0][j] = fmaf(iv[j], w01.x, acc[0][j]);
                    acc[1][j] = fmaf(iv[j], w01.y, acc[1][j]);
                    acc[2][j] = fmaf(iv[j], w23.x, acc[2][j]);
                    acc[3][j] = fmaf(iv[j], w23.y, acc[3][j]);
                    acc[4][j] = fmaf(iv[j], w45.x, acc[4][j]);
                    acc[5][j] = fmaf(iv[j], w45.y, acc[5][j]);
                }
            }
        }
    }

    float sst[6], sq[6];
#pragma unroll
    for (int c = 0; c < 6; ++c) { sst[c] = 0.f; sq[c] = 0.f; }
#pragma unroll
    for (int c = 0; c < 6; ++c) {
        float bv = bias[co0 + c];
#pragma unroll
        for (int j = 0; j < 12; ++j) {
            if (pv[j]) {
                int p = lane + j * 64;
                int r = p / 38, q = p - r * 38;
                float v = fmaxf(acc[c][j] + bv, 0.f);
                out[((n * 24 + co0 + c) * 38 + oh0 + r) * 38 + q] = v;
                sst[c] += v; sq[c] += v * v;
            }
        }
    }
#pragma unroll
    for (int o = 1; o < 64; o <<= 1) {
#pragma unroll
        for (int c = 0; c < 6; ++c) {
            sst[c] += __shfl_xor(sst[c], o);
            sq[c]  += __shfl_xor(sq[c], o);
        }
    }
    // channel groups are wave-partitioned: no collisions in red[]
    if (lane == 0) {
#pragma unroll
        for (int c = 0; c < 6; ++c) {
            red[(co0 + c) * 2]     = sst[c];
            red[(co0 + c) * 2 + 1] = sq[c];
        }
    }
    __syncthreads();
    if (tid < 48) atomicAdd(&statsOut[tid], red[tid]);  // one 48-lane atomic instr per block
}

// ============ conv2/3/4: CIN=24, LDS input tile (BN affine at stage time), weights via L1 (wT [216][24]) ==
template <int HIN, int WIN, int HOUT, int WOUT, int OHT, int NP>
__global__ __launch_bounds__(256, 2) void conv24_bn(const float* __restrict__ in,
                                                    const float* __restrict__ wT,
                                                    const float* __restrict__ bias,
                                                    const float* __restrict__ statsIn,
                                                    const float* __restrict__ gIn,
                                                    const float* __restrict__ bIn, float invcntIn,
                                                    float* __restrict__ out,
                                                    float* __restrict__ statsOut, int tilesPerImg)
{
    constexpr int IR = 2 * OHT + 1;
    constexpr int ICW = 2 * WOUT + 1;
    __shared__ float in_s[24 * IR * ICW];
    __shared__ float aff[48];
    __shared__ float red[48];

    int bid = blockIdx.x;
    int n = bid / tilesPerImg, tile = bid - n * tilesPerImg;
    int oh0 = tile * OHT;
    int tid = threadIdx.x;

    if (tid < 24) {
        float mean = statsIn[tid * 2] * invcntIn;
        float var  = statsIn[tid * 2 + 1] * invcntIn - mean * mean;
        float s    = gIn[tid] * rsqrtf(var + 1e-5f);
        aff[tid * 2] = s;
        aff[tid * 2 + 1] = bIn[tid] - mean * s;
    }
    __syncthreads();  // aff ready
    for (int idx = tid; idx < 24 * IR * ICW; idx += 256) {
        int ci = idx / (IR * ICW);
        int rem = idx - ci * (IR * ICW);
        int r = rem / ICW, c = rem - r * ICW;
        int ih = 2 * oh0 - 1 + r, iw = c - 1;
        float v = 0.f;
        if ((unsigned)ih < (unsigned)HIN && (unsigned)iw < (unsigned)WIN)
            v = aff[ci * 2] * in[((n * 24 + ci) * HIN + ih) * WIN + iw] + aff[ci * 2 + 1];
        in_s[idx] = v;
    }
    __syncthreads();

    int cg = tid >> 6, lane = tid & 63, co0 = cg * 6;
    int nvr = HOUT - oh0; if (nvr > OHT) nvr = OHT;
    int nposv = nvr * WOUT;
    int off[NP];
    bool pv[NP];
#pragma unroll
    for (int j = 0; j < NP; ++j) {
        int p = lane + j * 64;
        pv[j] = p < nposv;
        int pc = pv[j] ? p : 0;
        int r0 = pc / WOUT, c0 = pc - r0 * WOUT;
        off[j] = (r0 * 2) * ICW + c0 * 2;
    }
    float acc[6][NP];
#pragma unroll
    for (int c = 0; c < 6; ++c)
#pragma unroll
        for (int j = 0; j < NP; ++j) acc[c][j] = 0.f;

#pragma unroll 1
    for (int ci = 0; ci < 24; ++ci) {
        const float* ip = in_s + ci * (IR * ICW);
        const float* wp = wT + ci * 9 * 24 + co0;
#pragma unroll
        for (int kh = 0; kh < 3; ++kh) {
#pragma unroll
            for (int kw = 0; kw < 3; ++kw) {
                float iv[NP];
#pragma unroll
                for (int j = 0; j < NP; ++j) iv[j] = ip[off[j] + kh * ICW + kw];
                const float* wr = wp + (kh * 3 + kw) * 24;
                float2 w01 = *(const float2*)(wr);
                float2 w23 = *(const float2*)(wr + 2);
                float2 w45 = *(const float2*)(wr + 4);
#pragma unroll
                for (int j = 0; j < NP; ++j) {
                    acc[0][j] = fmaf(iv[j], w01.x, acc[0][j]);
                    acc[1][j] = fmaf(iv[j], w01.y, acc[1][j]);
                    acc[2][j] = fmaf(iv[j], w23.x, acc[2][j]);
                    acc[3][j] = fmaf(iv[j], w23.y, acc[3][j]);
                    acc[4][j] = fmaf(iv[j], w45.x, acc[4][j]);
                    acc[5][j] = fmaf(iv[j], w45.y, acc[5][j]);
                }
            }
        }
    }

    float sst[6], sq[6];
#pragma unroll
    for (int c = 0; c < 6; ++c) { sst[c] = 0.f; sq[c] = 0.f; }
#pragma unroll
    for (int c = 0; c < 6; ++c) {
        float bv = bias[co0 + c];
#pragma unroll
        for (int j = 0; j < NP; ++j) {
            if (pv[j]) {
                int p = lane + j * 64;
                int r = p / WOUT, q = p - r * WOUT;
                float v = fmaxf(acc[c][j] + bv, 0.f);
                out[((n * 24 + co0 + c) * HOUT + oh0 + r) * WOUT + q] = v;
                sst[c] += v; sq[c] += v * v;
            }
        }
    }
#pragma unroll
    for (int o = 1; o < 64; o <<= 1) {
#pragma unroll
        for (int c = 0; c < 6; ++c) {
            sst[c] += __shfl_xor(sst[c], o);
            sq[c]  += __shfl_xor(sq[c], o);
        }
    }
    if (lane == 0) {
#pragma unroll
        for (int c = 0; c < 6; ++c) {
            red[(co0 + c) * 2]     = sst[c];
            red[(co0 + c) * 2 + 1] = sq[c];
        }
    }
    __syncthreads();
    if (tid < 48) atomicAdd(&statsOut[tid], red[tid]);  // one 48-lane atomic instr per block
}

// ---------------- build bf16 features: xf26 = [BN4(conv4) 24ch, coords 2] ; qst bf16 ----------------
__global__ void build_features(const float* __restrict__ y4, const float* __restrict__ stats4,
                               const float* __restrict__ g4, const float* __restrict__ b4,
                               const float* __restrict__ qst,
                               bf16_t* __restrict__ xf26, bf16_t* __restrict__ qstb)
{
    int idx = blockIdx.x * 256 + threadIdx.x;
    if (idx < MB * 11) qstb[idx] = (bf16_t)qst[idx];
    if (idx >= MB * 25) return;
    int b = idx / 25, p = idx % 25;
    const float invcnt = 1.f / (MB * 25);
#pragma unroll
    for (int ch = 0; ch < 24; ++ch) {
        float mean = stats4[ch * 2] * invcnt;
        float var  = stats4[ch * 2 + 1] * invcnt - mean * mean;
        float s    = g4[ch] * rsqrtf(var + 1e-5f);
        float v    = s * y4[(b * 24 + ch) * 25 + p] + (b4[ch] - mean * s);
        xf26[idx * 26 + ch] = (bf16_t)v;
    }
    xf26[idx * 26 + 24] = (bf16_t)((p / 5.0f - 2.0f) * 0.5f);
    xf26[idx * 26 + 25] = (bf16_t)(((float)(p % 5) - 2.0f) * 0.5f);
}

// ------- weight prep: bf16 casts (gw1 padded K 63->64), fp32 transposes for f-MLP and conv wT --------
__global__ void prep_weights(const float* __restrict__ gw1, const float* __restrict__ gw2,
                             const float* __restrict__ gw3, const float* __restrict__ gw4,
                             const float* __restrict__ fw1, const float* __restrict__ fw2,
                             const float* __restrict__ c1w, const float* __restrict__ c2w,
                             const float* __restrict__ c3w, const float* __restrict__ c4w,
                             bf16_t* __restrict__ gw1p, bf16_t* __restrict__ gw2b,
                             bf16_t* __restrict__ gw3b, bf16_t* __restrict__ gw4b,
                             float* __restrict__ fw1T, float* __restrict__ fw2T,
                             float* __restrict__ wT1, float* __restrict__ wT2,
                             float* __restrict__ wT3, float* __restrict__ wT4)
{
    int idx = blockIdx.x * 256 + threadIdx.x;
    if (idx < 16384) {
        int nn = idx >> 6, k = idx & 63;
        gw1p[idx] = (k < 63) ? (bf16_t)gw1[nn * 63 + k] : (bf16_t)0.0f;
        return;
    }
    idx -= 16384;
    if (idx < 65536) { gw2b[idx] = (bf16_t)gw2[idx]; return; }
    idx -= 65536;
    if (idx < 65536) { gw3b[idx] = (bf16_t)gw3[idx]; return; }
    idx -= 65536;
    if (idx < 65536) { gw4b[idx] = (bf16_t)gw4[idx]; return; }
    idx -= 65536;
    if (idx < 65536) { int k = idx >> 8, nn = idx & 255; fw1T[idx] = fw1[nn * 256 + k]; return; }
    idx -= 65536;
    if (idx < 65536) { int k = idx >> 8, nn = idx & 255; fw2T[idx] = fw2[nn * 256 + k]; return; }
    idx -= 65536;
    if (idx < 648)   { int k = idx / 24, co = idx - k * 24; wT1[idx] = c1w[co * 27 + k]; return; }
    idx -= 648;
    if (idx < 5184)  { int k = idx / 24, co = idx - k * 24; wT2[idx] = c2w[co * 216 + k]; return; }
    idx -= 5184;
    if (idx < 5184)  { int k = idx / 24, co = idx - k * 24; wT3[idx] = c3w[co * 216 + k]; return; }
    idx -= 5184;
    if (idx < 5184)  { int k = idx / 24, co = idx - k * 24; wT4[idx] = c4w[co * 216 + k]; return; }
}

// ---------------- fused g-MLP over pair rows (MFMA bf16) ----------------
__device__ __forceinline__ void layer_mfma(const bf16_t* hs, const bf16_t* __restrict__ W, int K,
                                           int wid, int l15, int quad, f32x4 acc[MT][4])
{
#pragma unroll
    for (int mt = 0; mt < MT; ++mt)
#pragma unroll
        for (int nt = 0; nt < 4; ++nt) acc[mt][nt] = (f32x4)(0.0f);
    for (int ks = 0; ks < (K >> 5); ++ks) {
        bf16x8 af[MT];
#pragma unroll
        for (int mt = 0; mt < MT; ++mt)
            af[mt] = *(const bf16x8*)(hs + (mt * 16 + l15) * ST + ks * 32 + quad * 8);
#pragma unroll
        for (int nt = 0; nt < 4; ++nt) {
            int n = wid * 64 + nt * 16 + l15;
            bf16x8 bfr = *(const bf16x8*)(W + n * K + ks * 32 + quad * 8);
#pragma unroll
            for (int mt = 0; mt < MT; ++mt)
                acc[mt][nt] = __builtin_amdgcn_mfma_f32_16x16x32_bf16(af[mt], bfr, acc[mt][nt], 0, 0, 0);
        }
    }
}

__device__ __forceinline__ void store_relu(bf16_t* hs, const float* __restrict__ bias,
                                           int wid, int l15, int quad, f32x4 acc[MT][4])
{
#pragma unroll
    for (int nt = 0; nt < 4; ++nt) {
        int col = wid * 64 + nt * 16 + l15;
        float bv = bias[col];
#pragma unroll
        for (int mt = 0; mt < MT; ++mt) {
#pragma unroll
            for (int r = 0; r < 4; ++r) {
                int row = mt * 16 + quad * 4 + r;
                hs[row * ST + col] = (bf16_t)fmaxf(acc[mt][nt][r] + bv, 0.f);
            }
        }
    }
}

__global__ void __launch_bounds__(256, 2)
g_mlp(const bf16_t* __restrict__ xf26, const bf16_t* __restrict__ qstb,
      const bf16_t* __restrict__ W1, const bf16_t* __restrict__ W2,
      const bf16_t* __restrict__ W3, const bf16_t* __restrict__ W4,
      const float* __restrict__ b1, const float* __restrict__ b2,
      const float* __restrict__ b3, const float* __restrict__ b4,
      float* __restrict__ xg)
{
    __shared__ __align__(16) bf16_t hs[ROWS * ST];
    int b    = blockIdx.x / TILES_PER_B;
    int tile = blockIdx.x % TILES_PER_B;
    int tid  = threadIdx.x;

    {
        int m = tid >> 1, hf = tid & 1;
        if (m < ROWS) {
            int p = tile * ROWS + m;
            bf16_t* dst = hs + m * ST + hf * 32;
            if (p < 625) {
                int a = p / 25, c = p - a * 25;
                const bf16_t* f1 = xf26 + (b * 25 + c) * 26;
                const bf16_t* f2 = xf26 + (b * 25 + a) * 26;
                const bf16_t* f3 = qstb + b * 11;
#pragma unroll
                for (int j = 0; j < 32; ++j) {
                    int col = hf * 32 + j;
                    bf16_t u = (bf16_t)0.0f;
                    if (col < 26) u = f1[col];
                    else if (col < 52) u = f2[col - 26];
                    else if (col < 63) u = f3[col - 52];
                    dst[j] = u;
                }
            } else {
#pragma unroll
                for (int j = 0; j < 32; ++j) dst[j] = (bf16_t)0.0f;
            }
        }
    }
    __syncthreads();

    int wid = tid >> 6, lane = tid & 63, l15 = lane & 15, quad = lane >> 4;
    f32x4 acc[MT][4];

    layer_mfma(hs, W1, 64, wid, l15, quad, acc);
    __syncthreads(); store_relu(hs, b1, wid, l15, quad, acc); __syncthreads();
    layer_mfma(hs, W2, 256, wid, l15, quad, acc);
    __syncthreads(); store_relu(hs, b2, wid, l15, quad, acc); __syncthreads();
    layer_mfma(hs, W3, 256, wid, l15, quad, acc);
    __syncthreads(); store_relu(hs, b3, wid, l15, quad, acc); __syncthreads();
    layer_mfma(hs, W4, 256, wid, l15, quad, acc);

    int nvalid = 625 - tile * ROWS; if (nvalid > ROWS) nvalid = ROWS;
#pragma unroll
    for (int nt = 0; nt < 4; ++nt) {
        int col = wid * 64 + nt * 16 + l15;
        float bv = b4[col];
        float s = 0.f;
#pragma unroll
        for (int mt = 0; mt < MT; ++mt) {
#pragma unroll
            for (int r = 0; r < 4; ++r) {
                int row = mt * 16 + quad * 4 + r;
                float v = fmaxf(acc[mt][nt][r] + bv, 0.f);
                s += (row < nvalid) ? v : 0.f;
            }
        }
        s += __shfl_xor(s, 16);
        s += __shfl_xor(s, 32);
        if (quad == 0) atomicAdd(&xg[b * 256 + col], s);
    }
}

// ---------------- f-MLP (fp32) + log_softmax, one block per batch element ----------------
__global__ void f_mlp(const float* __restrict__ xg, const float* __restrict__ fw1T, const float* __restrict__ fb1,
                      const float* __restrict__ fw2T, const float* __restrict__ fb2,
                      const float* __restrict__ fw3, const float* __restrict__ fb3,
                      float* __restrict__ out)
{
    __shared__ float xa[256], xb[256], lg[10];
    int b = blockIdx.x, t = threadIdx.x;
    xa[t] = xg[b * 256 + t];
    __syncthreads();
    float a = fb1[t];
    for (int k = 0; k < 256; ++k) a += fw1T[k * 256 + t] * xa[k];
    xb[t] = fmaxf(a, 0.f);
    __syncthreads();
    a = fb2[t];
    for (int k = 0; k < 256; ++k) a += fw2T[k * 256 + t] * xb[k];
    xa[t] = fmaxf(a, 0.f);
    __syncthreads();
    if (t < 10) {
        float s = fb3[t];
        for (int k = 0; k < 256; ++k) s += fw3[t * 256 + k] * xa[k];
        lg[t] = s;
    }
    __syncthreads();
    if (t == 0) {
        float m = lg[0];
        for (int i = 1; i < 10; ++i) m = fmaxf(m, lg[i]);
        float s = 0.f;
        for (int i = 0; i < 10; ++i) s += expf(lg[i] - m);
        float ls = m + logf(s);
        for (int i = 0; i < 10; ++i) out[b * 10 + i] = lg[i] - ls;
    }
}

// ---------------- launch ----------------
extern "C" void kernel_launch(void* const* d_in, const int* in_sizes, int n_in,
                              void* d_out, int out_size, void* d_ws, size_t ws_size,
                              hipStream_t stream)
{
    (void)in_sizes; (void)n_in; (void)out_size; (void)ws_size;
    const float* img  = (const float*)d_in[0];
    const float* qst  = (const float*)d_in[1];
    const float* c1w  = (const float*)d_in[2];
    const float* c1b  = (const float*)d_in[3];
    const float* bn1g = (const float*)d_in[4];
    const float* bn1b = (const float*)d_in[5];
    const float* c2w  = (const float*)d_in[6];
    const float* c2b  = (const float*)d_in[7];
    const float* bn2g = (const float*)d_in[8];
    const float* bn2b = (const float*)d_in[9];
    const float* c3w  = (const float*)d_in[10];
    const float* c3b  = (const float*)d_in[11];
    const float* bn3g = (const float*)d_in[12];
    const float* bn3b = (const float*)d_in[13];
    const float* c4w  = (const float*)d_in[14];
    const float* c4b  = (const float*)d_in[15];
    const float* bn4g = (const float*)d_in[16];
    const float* bn4b = (const float*)d_in[17];
    const float* gw1  = (const float*)d_in[18];
    const float* gb1  = (const float*)d_in[19];
    const float* gw2  = (const float*)d_in[20];
    const float* gb2  = (const float*)d_in[21];
    const float* gw3  = (const float*)d_in[22];
    const float* gb3  = (const float*)d_in[23];
    const float* gw4  = (const float*)d_in[24];
    const float* gb4  = (const float*)d_in[25];
    const float* fw1  = (const float*)d_in[26];
    const float* fb1  = (const float*)d_in[27];
    const float* fw2  = (const float*)d_in[28];
    const float* fb2  = (const float*)d_in[29];
    const float* fw3  = (const float*)d_in[30];
    const float* fb3  = (const float*)d_in[31];

    const int Y1 = 512 * 24 * 38 * 38;
    const int Y2 = 512 * 24 * 19 * 19;
    const int Y3 = 512 * 24 * 10 * 10;
    const int Y4 = 512 * 24 * 5 * 5;

    float* fp = (float*)d_ws;
    float* y1    = fp;  fp += Y1;
    float* y2    = fp;  fp += Y2;
    float* y3    = fp;  fp += Y3;
    float* y4    = fp;  fp += Y4;
    float* stats = fp;  fp += 192;       // [4 layers][24 ch][sum, sumsq]
    float* xg    = fp;  fp += 512 * 256;
    float* fw1T  = fp;  fp += 65536;
    float* fw2T  = fp;  fp += 65536;
    float* wT1   = fp;  fp += 648;       // conv weights transposed [k][24]
    float* wT2   = fp;  fp += 5184;
    float* wT3   = fp;  fp += 5184;
    float* wT4   = fp;  fp += 5184;
    bf16_t* bp   = (bf16_t*)fp;
    bf16_t* xf26 = bp;  bp += 512 * 25 * 26;
    bf16_t* qstb = bp;  bp += 512 * 11;
    bf16_t* gw1p = bp;  bp += 256 * 64;
    bf16_t* gw2b = bp;  bp += 65536;
    bf16_t* gw3b = bp;  bp += 65536;
    bf16_t* gw4b = bp;  bp += 65536;

    hipMemsetAsync(stats, 0, 192 * sizeof(float), stream);
    hipMemsetAsync(xg, 0, 512 * 256 * sizeof(float), stream);

    prep_weights<<<1408, 256, 0, stream>>>(gw1, gw2, gw3, gw4, fw1, fw2, c1w, c2w, c3w, c4w,
                                           gw1p, gw2b, gw3b, gw4b, fw1T, fw2T,
                                           wT1, wT2, wT3, wT4);

    // conv1: 512 images x 2 row-tiles
    conv1_bn<<<1024, 256, 0, stream>>>(img, wT1, c1b, y1, stats + 0);

    // conv2: 38x38 -> 19x19, 4 row-tiles of 5
    conv24_bn<38, 38, 19, 19, 5, 2><<<2048, 256, 0, stream>>>(
        y1, wT2, c2b, stats + 0, bn1g, bn1b, 1.f / (512.f * 1444.f),
        y2, stats + 48, 4);

    // conv3: 19x19 -> 10x10, single tile
    conv24_bn<19, 19, 10, 10, 10, 2><<<512, 256, 0, stream>>>(
        y2, wT3, c3b, stats + 48, bn2g, bn2b, 1.f / (512.f * 361.f),
        y3, stats + 96, 1);

    // conv4: 10x10 -> 5x5, single tile
    conv24_bn<10, 10, 5, 5, 5, 1><<<512, 256, 0, stream>>>(
        y3, wT4, c4b, stats + 96, bn3g, bn3b, 1.f / (512.f * 100.f),
        y4, stats + 144, 1);

    build_features<<<50, 256, 0, stream>>>(y4, stats + 144, bn4g, bn4b, qst, xf26, qstb);

    g_mlp<<<512 * TILES_PER_B, 256, 0, stream>>>(xf26, qstb, gw1p, gw2b, gw3b, gw4b,
                                                 gb1, gb2, gb3, gb4, xg);

    f_mlp<<<512, 256, 0, stream>>>(xg, fw1T, fb1, fw2T, fb2, fw3, fb3, (float*)d_out);
}

// Round 5
// 601.443 us; speedup vs baseline: 2.6923x; 1.0890x over previous
//
#include <hip/hip_runtime.h>

typedef __bf16 bf16_t;
typedef __bf16 bf16x8 __attribute__((ext_vector_type(8)));
typedef __bf16 bf16x4 __attribute__((ext_vector_type(4)));
typedef float f32x16 __attribute__((ext_vector_type(16)));

#define MB 512
#define GROWS 128     // pair rows per g-block (4 mtiles of 32)
#define GT_PER_B 5    // ceil(625/128)

// ================= conv1: CIN=3, 75x75 -> 38x38, LDS input tile, weights via L1 (wT [27][24]) ============
__global__ __launch_bounds__(256, 2) void conv1_bn(const float* __restrict__ img,
                                                   const float* __restrict__ wT,
                                                   const float* __restrict__ bias,
                                                   float* __restrict__ out,
                                                   float* __restrict__ statsOut)
{
    __shared__ float in_s[3 * 39 * 77];   // 36,036 B
    __shared__ float red[48];
    int bid = blockIdx.x;
    int n = bid >> 1, tile = bid & 1;
    int oh0 = tile * 19;
    int tid = threadIdx.x;

    for (int idx = tid; idx < 3 * 39 * 77; idx += 256) {
        int ci = idx / (39 * 77);
        int rem = idx - ci * (39 * 77);
        int r = rem / 77, c = rem - r * 77;
        int ih = 2 * oh0 - 1 + r, iw = c - 1;
        float v = 0.f;
        if ((unsigned)ih < 75u && (unsigned)iw < 75u)
            v = img[((n * 3 + ci) * 75 + ih) * 75 + iw];
        in_s[idx] = v;
    }
    __syncthreads();

    int cg = tid >> 6, lane = tid & 63, co0 = cg * 6;
    int off[12];
    bool pv[12];
#pragma unroll
    for (int j = 0; j < 12; ++j) {
        int p = lane + j * 64;
        pv[j] = p < 722;
        int pc = pv[j] ? p : 0;
        int r0 = pc / 38, c0 = pc - r0 * 38;
        off[j] = (r0 * 2) * 77 + c0 * 2;
    }
    float acc[6][12];
#pragma unroll
    for (int c = 0; c < 6; ++c)
#pragma unroll
        for (int j = 0; j < 12; ++j) acc[c][j] = 0.f;

#pragma unroll 1
    for (int ci = 0; ci < 3; ++ci) {
        const float* ip = in_s + ci * (39 * 77);
        const float* wp = wT + ci * 9 * 24 + co0;
#pragma unroll
        for (int kh = 0; kh < 3; ++kh) {
#pragma unroll
            for (int kw = 0; kw < 3; ++kw) {
                float iv[12];
#pragma unroll
                for (int j = 0; j < 12; ++j) iv[j] = ip[off[j] + kh * 77 + kw];
                const float* wr = wp + (kh * 3 + kw) * 24;
                float2 w01 = *(const float2*)(wr);
                float2 w23 = *(const float2*)(wr + 2);
                float2 w45 = *(const float2*)(wr + 4);
#pragma unroll
                for (int j = 0; j < 12; ++j) {
                    acc[0][j] = fmaf(iv[j], w01.x, acc[0][j]);
                    acc[1][j] = fmaf(iv[j], w01.y, acc[1][j]);
                    acc[2][j] = fmaf(iv[j], w23.x, acc[2][j]);
                    acc[3][j] = fmaf(iv[j], w23.y, acc[3][j]);
                    acc[4][j] = fmaf(iv[j], w45.x, acc[4][j]);
                    acc[5][j] = fmaf(iv[j], w45.y, acc[5][j]);
                }
            }
        }
    }

    float sst[6], sq[6];
#pragma unroll
    for (int c = 0; c < 6; ++c) { sst[c] = 0.f; sq[c] = 0.f; }
#pragma unroll
    for (int c = 0; c < 6; ++c) {
        float bv = bias[co0 + c];
#pragma unroll
        for (int j = 0; j < 12; ++j) {
            if (pv[j]) {
                int p = lane + j * 64;
                int r = p / 38, q = p - r * 38;
                float v = fmaxf(acc[c][j] + bv, 0.f);
                out[((n * 24 + co0 + c) * 38 + oh0 + r) * 38 + q] = v;
                sst[c] += v; sq[c] += v * v;
            }
        }
    }
#pragma unroll
    for (int o = 1; o < 64; o <<= 1) {
#pragma unroll
        for (int c = 0; c < 6; ++c) {
            sst[c] += __shfl_xor(sst[c], o);
            sq[c]  += __shfl_xor(sq[c], o);
        }
    }
    if (lane == 0) {
#pragma unroll
        for (int c = 0; c < 6; ++c) {
            red[(co0 + c) * 2]     = sst[c];
            red[(co0 + c) * 2 + 1] = sq[c];
        }
    }
    __syncthreads();
    if (tid < 48) atomicAdd(&statsOut[tid], red[tid]);
}

// ============ conv2/3/4: CIN=24, LDS input tile (BN affine at stage time), weights via L1 (wT [216][24]) ==
template <int HIN, int WIN, int HOUT, int WOUT, int OHT, int NP>
__global__ __launch_bounds__(256, 2) void conv24_bn(const float* __restrict__ in,
                                                    const float* __restrict__ wT,
                                                    const float* __restrict__ bias,
                                                    const float* __restrict__ statsIn,
                                                    const float* __restrict__ gIn,
                                                    const float* __restrict__ bIn, float invcntIn,
                                                    float* __restrict__ out,
                                                    float* __restrict__ statsOut, int tilesPerImg)
{
    constexpr int IR = 2 * OHT + 1;
    constexpr int ICW = 2 * WOUT + 1;
    __shared__ float in_s[24 * IR * ICW];
    __shared__ float aff[48];
    __shared__ float red[48];

    int bid = blockIdx.x;
    int n = bid / tilesPerImg, tile = bid - n * tilesPerImg;
    int oh0 = tile * OHT;
    int tid = threadIdx.x;

    if (tid < 24) {
        float mean = statsIn[tid * 2] * invcntIn;
        float var  = statsIn[tid * 2 + 1] * invcntIn - mean * mean;
        float s    = gIn[tid] * rsqrtf(var + 1e-5f);
        aff[tid * 2] = s;
        aff[tid * 2 + 1] = bIn[tid] - mean * s;
    }
    __syncthreads();
    for (int idx = tid; idx < 24 * IR * ICW; idx += 256) {
        int ci = idx / (IR * ICW);
        int rem = idx - ci * (IR * ICW);
        int r = rem / ICW, c = rem - r * ICW;
        int ih = 2 * oh0 - 1 + r, iw = c - 1;
        float v = 0.f;
        if ((unsigned)ih < (unsigned)HIN && (unsigned)iw < (unsigned)WIN)
            v = aff[ci * 2] * in[((n * 24 + ci) * HIN + ih) * WIN + iw] + aff[ci * 2 + 1];
        in_s[idx] = v;
    }
    __syncthreads();

    int cg = tid >> 6, lane = tid & 63, co0 = cg * 6;
    int nvr = HOUT - oh0; if (nvr > OHT) nvr = OHT;
    int nposv = nvr * WOUT;
    int off[NP];
    bool pv[NP];
#pragma unroll
    for (int j = 0; j < NP; ++j) {
        int p = lane + j * 64;
        pv[j] = p < nposv;
        int pc = pv[j] ? p : 0;
        int r0 = pc / WOUT, c0 = pc - r0 * WOUT;
        off[j] = (r0 * 2) * ICW + c0 * 2;
    }
    float acc[6][NP];
#pragma unroll
    for (int c = 0; c < 6; ++c)
#pragma unroll
        for (int j = 0; j < NP; ++j) acc[c][j] = 0.f;

#pragma unroll 1
    for (int ci = 0; ci < 24; ++ci) {
        const float* ip = in_s + ci * (IR * ICW);
        const float* wp = wT + ci * 9 * 24 + co0;
#pragma unroll
        for (int kh = 0; kh < 3; ++kh) {
#pragma unroll
            for (int kw = 0; kw < 3; ++kw) {
                float iv[NP];
#pragma unroll
                for (int j = 0; j < NP; ++j) iv[j] = ip[off[j] + kh * ICW + kw];
                const float* wr = wp + (kh * 3 + kw) * 24;
                float2 w01 = *(const float2*)(wr);
                float2 w23 = *(const float2*)(wr + 2);
                float2 w45 = *(const float2*)(wr + 4);
#pragma unroll
                for (int j = 0; j < NP; ++j) {
                    acc[0][j] = fmaf(iv[j], w01.x, acc[0][j]);
                    acc[1][j] = fmaf(iv[j], w01.y, acc[1][j]);
                    acc[2][j] = fmaf(iv[j], w23.x, acc[2][j]);
                    acc[3][j] = fmaf(iv[j], w23.y, acc[3][j]);
                    acc[4][j] = fmaf(iv[j], w45.x, acc[4][j]);
                    acc[5][j] = fmaf(iv[j], w45.y, acc[5][j]);
                }
            }
        }
    }

    float sst[6], sq[6];
#pragma unroll
    for (int c = 0; c < 6; ++c) { sst[c] = 0.f; sq[c] = 0.f; }
#pragma unroll
    for (int c = 0; c < 6; ++c) {
        float bv = bias[co0 + c];
#pragma unroll
        for (int j = 0; j < NP; ++j) {
            if (pv[j]) {
                int p = lane + j * 64;
                int r = p / WOUT, q = p - r * WOUT;
                float v = fmaxf(acc[c][j] + bv, 0.f);
                out[((n * 24 + co0 + c) * HOUT + oh0 + r) * WOUT + q] = v;
                sst[c] += v; sq[c] += v * v;
            }
        }
    }
#pragma unroll
    for (int o = 1; o < 64; o <<= 1) {
#pragma unroll
        for (int c = 0; c < 6; ++c) {
            sst[c] += __shfl_xor(sst[c], o);
            sq[c]  += __shfl_xor(sq[c], o);
        }
    }
    if (lane == 0) {
#pragma unroll
        for (int c = 0; c < 6; ++c) {
            red[(co0 + c) * 2]     = sst[c];
            red[(co0 + c) * 2 + 1] = sq[c];
        }
    }
    __syncthreads();
    if (tid < 48) atomicAdd(&statsOut[tid], red[tid]);
}

// ---------------- build bf16 features: xf26 = [BN4(conv4) 24ch, coords 2] ; qst bf16 ----------------
__global__ void build_features(const float* __restrict__ y4, const float* __restrict__ stats4,
                               const float* __restrict__ g4, const float* __restrict__ b4,
                               const float* __restrict__ qst,
                               bf16_t* __restrict__ xf26, bf16_t* __restrict__ qstb)
{
    int idx = blockIdx.x * 256 + threadIdx.x;
    if (idx < MB * 11) qstb[idx] = (bf16_t)qst[idx];
    if (idx >= MB * 25) return;
    int b = idx / 25, p = idx % 25;
    const float invcnt = 1.f / (MB * 25);
#pragma unroll
    for (int ch = 0; ch < 24; ++ch) {
        float mean = stats4[ch * 2] * invcnt;
        float var  = stats4[ch * 2 + 1] * invcnt - mean * mean;
        float s    = g4[ch] * rsqrtf(var + 1e-5f);
        float v    = s * y4[(b * 24 + ch) * 25 + p] + (b4[ch] - mean * s);
        xf26[idx * 26 + ch] = (bf16_t)v;
    }
    xf26[idx * 26 + 24] = (bf16_t)((p / 5.0f - 2.0f) * 0.5f);
    xf26[idx * 26 + 25] = (bf16_t)(((float)(p % 5) - 2.0f) * 0.5f);
}

// ------- weight prep: g-weights in MFMA-A-frag order, fp32 transposes for f-MLP, conv wT --------
// Wf layout per layer: [nt (N/32)][ks (K/16)][lane 0..63][j 0..7]
//   element = W[nt*32 + (lane&31)][ks*16 + (lane>>5)*8 + j]
__device__ __forceinline__ void frag256(int idx, const float* __restrict__ gw, bf16_t* __restrict__ Wf)
{
    int j = idx & 7, lane = (idx >> 3) & 63, ks = (idx >> 9) & 15, nt = idx >> 13;
    int n = nt * 32 + (lane & 31), k = ks * 16 + (lane >> 5) * 8 + j;
    Wf[idx] = (bf16_t)gw[n * 256 + k];
}

// total work items: 16384 + 3*65536 + 2*65536 + 648 + 3*5184 = 360,264 -> grid 1408x256 = 360,448
__global__ void prep_weights(const float* __restrict__ gw1, const float* __restrict__ gw2,
                             const float* __restrict__ gw3, const float* __restrict__ gw4,
                             const float* __restrict__ fw1, const float* __restrict__ fw2,
                             const float* __restrict__ c1w, const float* __restrict__ c2w,
                             const float* __restrict__ c3w, const float* __restrict__ c4w,
                             bf16_t* __restrict__ W1f, bf16_t* __restrict__ W2f,
                             bf16_t* __restrict__ W3f, bf16_t* __restrict__ W4f,
                             float* __restrict__ fw1T, float* __restrict__ fw2T,
                             float* __restrict__ wT1, float* __restrict__ wT2,
                             float* __restrict__ wT3, float* __restrict__ wT4)
{
    int idx = blockIdx.x * 256 + threadIdx.x;
    if (idx < 16384) {  // W1: K=64 (63 + zero pad), [8 nt][4 ks][64][8]
        int j = idx & 7, lane = (idx >> 3) & 63, ks = (idx >> 9) & 3, nt = idx >> 11;
        int n = nt * 32 + (lane & 31), k = ks * 16 + (lane >> 5) * 8 + j;
        W1f[idx] = (k < 63) ? (bf16_t)gw1[n * 63 + k] : (bf16_t)0.0f;
        return;
    }
    idx -= 16384;
    if (idx < 65536) { frag256(idx, gw2, W2f); return; }
    idx -= 65536;
    if (idx < 65536) { frag256(idx, gw3, W3f); return; }
    idx -= 65536;
    if (idx < 65536) { frag256(idx, gw4, W4f); return; }
    idx -= 65536;
    if (idx < 65536) { int k = idx >> 8, nn = idx & 255; fw1T[idx] = fw1[nn * 256 + k]; return; }
    idx -= 65536;
    if (idx < 65536) { int k = idx >> 8, nn = idx & 255; fw2T[idx] = fw2[nn * 256 + k]; return; }
    idx -= 65536;
    if (idx < 648)   { int k = idx / 24, co = idx - k * 24; wT1[idx] = c1w[co * 27 + k]; return; }
    idx -= 648;
    if (idx < 5184)  { int k = idx / 24, co = idx - k * 24; wT2[idx] = c2w[co * 216 + k]; return; }
    idx -= 5184;
    if (idx < 5184)  { int k = idx / 24, co = idx - k * 24; wT3[idx] = c3w[co * 216 + k]; return; }
    idx -= 5184;
    if (idx < 5184)  { int k = idx / 24, co = idx - k * 24; wT4[idx] = c4w[co * 216 + k]; return; }
}

// ---------------- fused g-MLP: 32x32x16 MFMA, swapped operands (A=W, B=h^T), swizzled LDS ----------------
// LDS: hs[m][256], stride 256 bf16 (512B, exact 64KB). 16B chunk c at row m lives at chunk slot c^(m&31).
// Wave wid owns n-tiles {2*wid, 2*wid+1} (64 n) x all 128 rows. W read once per block.
// D[n'][m]: col=lane&31 -> m ; row=(reg&3)+8*(reg>>2)+4*(lane>>5) -> n within tile.

template <int NKS>  // K/16: 4 for layer1, 16 for layers 2-4
__device__ __forceinline__ void g_layer(const bf16_t* hs, const bf16_t* __restrict__ Wf,
                                        int wid, int lane, f32x16 acc[4][2])
{
    int m31 = lane & 31, half = lane >> 5;
#pragma unroll
    for (int mt = 0; mt < 4; ++mt)
#pragma unroll
        for (int nt = 0; nt < 2; ++nt) acc[mt][nt] = (f32x16)(0.f);
#pragma unroll
    for (int ks = 0; ks < NKS; ++ks) {
        int kc = ks * 2 + half;
        bf16x8 hf[4];
#pragma unroll
        for (int mt = 0; mt < 4; ++mt) {
            int m = mt * 32 + m31;
            hf[mt] = *(const bf16x8*)(hs + m * 256 + ((kc ^ m31) << 3));
        }
        bf16x8 wf[2];
#pragma unroll
        for (int nt = 0; nt < 2; ++nt)
            wf[nt] = *(const bf16x8*)(Wf + (size_t)(((wid * 2 + nt) * NKS + ks) * 64 + lane) * 8);
#pragma unroll
        for (int nt = 0; nt < 2; ++nt)
#pragma unroll
            for (int mt = 0; mt < 4; ++mt)
                acc[mt][nt] = __builtin_amdgcn_mfma_f32_32x32x16_bf16(wf[nt], hf[mt], acc[mt][nt], 0, 0, 0);
    }
}

__device__ __forceinline__ void g_store(bf16_t* hs, const float* __restrict__ bias,
                                        int wid, int lane, f32x16 acc[4][2])
{
    int m31 = lane & 31, half = lane >> 5;
#pragma unroll
    for (int mt = 0; mt < 4; ++mt) {
        int m = mt * 32 + m31;
#pragma unroll
        for (int nt = 0; nt < 2; ++nt) {
            int nbase = (wid * 2 + nt) * 32;
#pragma unroll
            for (int g = 0; g < 4; ++g) {
                int n0 = nbase + g * 8 + half * 4;
                float4 bv = *(const float4*)(bias + n0);
                bf16x4 v;
                v[0] = (bf16_t)fmaxf(acc[mt][nt][g * 4 + 0] + bv.x, 0.f);
                v[1] = (bf16_t)fmaxf(acc[mt][nt][g * 4 + 1] + bv.y, 0.f);
                v[2] = (bf16_t)fmaxf(acc[mt][nt][g * 4 + 2] + bv.z, 0.f);
                v[3] = (bf16_t)fmaxf(acc[mt][nt][g * 4 + 3] + bv.w, 0.f);
                int chunk = n0 >> 3;  // half*4 < 8, so chunk = (nbase + g*8) >> 3
                *(bf16x4*)(hs + m * 256 + ((chunk ^ m31) << 3) + (half << 2)) = v;
            }
        }
    }
}

__global__ void __launch_bounds__(256, 2)
g_mlp(const bf16_t* __restrict__ xf26, const bf16_t* __restrict__ qstb,
      const bf16_t* __restrict__ W1f, const bf16_t* __restrict__ W2f,
      const bf16_t* __restrict__ W3f, const bf16_t* __restrict__ W4f,
      const float* __restrict__ b1, const float* __restrict__ b2,
      const float* __restrict__ b3, const float* __restrict__ b4,
      float* __restrict__ xg)
{
    __shared__ __align__(16) bf16_t hs[GROWS * 256];   // 65,536 B
    int b    = blockIdx.x / GT_PER_B;
    int tile = blockIdx.x % GT_PER_B;
    int tid  = threadIdx.x;

    // stage features (64 bf16 per row -> chunks 0..7, swizzled)
    for (int i = tid; i < GROWS * 8; i += 256) {
        int m = i >> 3, c = i & 7;
        int p = tile * GROWS + m;
        bf16x8 v;
        if (p < 625) {
            int a = p / 25, cp = p - a * 25;
            const bf16_t* f1 = xf26 + (b * 25 + cp) * 26;
            const bf16_t* f2 = xf26 + (b * 25 + a) * 26;
            const bf16_t* f3 = qstb + b * 11;
#pragma unroll
            for (int j = 0; j < 8; ++j) {
                int col = c * 8 + j;
                bf16_t u = (bf16_t)0.0f;
                if (col < 26) u = f1[col];
                else if (col < 52) u = f2[col - 26];
                else if (col < 63) u = f3[col - 52];
                v[j] = u;
            }
        } else {
#pragma unroll
            for (int j = 0; j < 8; ++j) v[j] = (bf16_t)0.0f;
        }
        *(bf16x8*)(hs + m * 256 + ((c ^ (m & 31)) << 3)) = v;
    }
    __syncthreads();

    int wid = tid >> 6, lane = tid & 63;
    int m31 = lane & 31, half = lane >> 5;
    f32x16 acc[4][2];

    g_layer<4>(hs, W1f, wid, lane, acc);
    __syncthreads(); g_store(hs, b1, wid, lane, acc); __syncthreads();
    g_layer<16>(hs, W2f, wid, lane, acc);
    __syncthreads(); g_store(hs, b2, wid, lane, acc); __syncthreads();
    g_layer<16>(hs, W3f, wid, lane, acc);
    __syncthreads(); g_store(hs, b3, wid, lane, acc); __syncthreads();
    g_layer<16>(hs, W4f, wid, lane, acc);

    // epilogue: relu(acc + b4), mask invalid rows, sum over m, atomic into xg
#pragma unroll
    for (int nt = 0; nt < 2; ++nt) {
        int nbase = (wid * 2 + nt) * 32;
        float bf[16];
#pragma unroll
        for (int r = 0; r < 16; ++r)
            bf[r] = b4[nbase + (r & 3) + 8 * (r >> 2) + 4 * half];
        f32x16 t = (f32x16)(0.f);
#pragma unroll
        for (int mt = 0; mt < 4; ++mt) {
            int p = tile * GROWS + mt * 32 + m31;
            if (p < 625) {
#pragma unroll
                for (int r = 0; r < 16; ++r)
                    t[r] += fmaxf(acc[mt][nt][r] + bf[r], 0.f);
            }
        }
#pragma unroll
        for (int off = 1; off < 32; off <<= 1) {
#pragma unroll
            for (int r = 0; r < 16; ++r) t[r] += __shfl_xor(t[r], off);
        }
        if (m31 == 0) {
#pragma unroll
            for (int r = 0; r < 16; ++r) {
                int nn = nbase + (r & 3) + 8 * (r >> 2) + 4 * half;
                atomicAdd(&xg[b * 256 + nn], t[r]);
            }
        }
    }
}

// ---------------- f-MLP (fp32) + log_softmax, one block per batch element ----------------
__global__ void f_mlp(const float* __restrict__ xg, const float* __restrict__ fw1T, const float* __restrict__ fb1,
                      const float* __restrict__ fw2T, const float* __restrict__ fb2,
                      const float* __restrict__ fw3, const float* __restrict__ fb3,
                      float* __restrict__ out)
{
    __shared__ float xa[256], xb[256], lg[10];
    int b = blockIdx.x, t = threadIdx.x;
    xa[t] = xg[b * 256 + t];
    __syncthreads();
    float a = fb1[t];
    for (int k = 0; k < 256; ++k) a += fw1T[k * 256 + t] * xa[k];
    xb[t] = fmaxf(a, 0.f);
    __syncthreads();
    a = fb2[t];
    for (int k = 0; k < 256; ++k) a += fw2T[k * 256 + t] * xb[k];
    xa[t] = fmaxf(a, 0.f);
    __syncthreads();
    if (t < 10) {
        float s = fb3[t];
        for (int k = 0; k < 256; ++k) s += fw3[t * 256 + k] * xa[k];
        lg[t] = s;
    }
    __syncthreads();
    if (t == 0) {
        float m = lg[0];
        for (int i = 1; i < 10; ++i) m = fmaxf(m, lg[i]);
        float s = 0.f;
        for (int i = 0; i < 10; ++i) s += expf(lg[i] - m);
        float ls = m + logf(s);
        for (int i = 0; i < 10; ++i) out[b * 10 + i] = lg[i] - ls;
    }
}

// ---------------- launch ----------------
extern "C" void kernel_launch(void* const* d_in, const int* in_sizes, int n_in,
                              void* d_out, int out_size, void* d_ws, size_t ws_size,
                              hipStream_t stream)
{
    (void)in_sizes; (void)n_in; (void)out_size; (void)ws_size;
    const float* img  = (const float*)d_in[0];
    const float* qst  = (const float*)d_in[1];
    const float* c1w  = (const float*)d_in[2];
    const float* c1b  = (const float*)d_in[3];
    const float* bn1g = (const float*)d_in[4];
    const float* bn1b = (const float*)d_in[5];
    const float* c2w  = (const float*)d_in[6];
    const float* c2b  = (const float*)d_in[7];
    const float* bn2g = (const float*)d_in[8];
    const float* bn2b = (const float*)d_in[9];
    const float* c3w  = (const float*)d_in[10];
    const float* c3b  = (const float*)d_in[11];
    const float* bn3g = (const float*)d_in[12];
    const float* bn3b = (const float*)d_in[13];
    const float* c4w  = (const float*)d_in[14];
    const float* c4b  = (const float*)d_in[15];
    const float* bn4g = (const float*)d_in[16];
    const float* bn4b = (const float*)d_in[17];
    const float* gw1  = (const float*)d_in[18];
    const float* gb1  = (const float*)d_in[19];
    const float* gw2  = (const float*)d_in[20];
    const float* gb2  = (const float*)d_in[21];
    const float* gw3  = (const float*)d_in[22];
    const float* gb3  = (const float*)d_in[23];
    const float* gw4  = (const float*)d_in[24];
    const float* gb4  = (const float*)d_in[25];
    const float* fw1  = (const float*)d_in[26];
    const float* fb1  = (const float*)d_in[27];
    const float* fw2  = (const float*)d_in[28];
    const float* fb2  = (const float*)d_in[29];
    const float* fw3  = (const float*)d_in[30];
    const float* fb3  = (const float*)d_in[31];

    const int Y1 = 512 * 24 * 38 * 38;
    const int Y2 = 512 * 24 * 19 * 19;
    const int Y3 = 512 * 24 * 10 * 10;
    const int Y4 = 512 * 24 * 5 * 5;

    float* fp = (float*)d_ws;
    float* y1    = fp;  fp += Y1;
    float* y2    = fp;  fp += Y2;
    float* y3    = fp;  fp += Y3;
    float* y4    = fp;  fp += Y4;
    float* stats = fp;  fp += 192;       // [4 layers][24 ch][sum, sumsq]
    float* xg    = fp;  fp += 512 * 256;
    float* fw1T  = fp;  fp += 65536;
    float* fw2T  = fp;  fp += 65536;
    float* wT1   = fp;  fp += 648;       // conv weights transposed [k][24]
    float* wT2   = fp;  fp += 5184;
    float* wT3   = fp;  fp += 5184;
    float* wT4   = fp;  fp += 5184;
    bf16_t* bp   = (bf16_t*)fp;
    bf16_t* xf26 = bp;  bp += 512 * 25 * 26;
    bf16_t* qstb = bp;  bp += 512 * 11;
    bf16_t* W1f  = bp;  bp += 16384;     // g-weights in MFMA frag order
    bf16_t* W2f  = bp;  bp += 65536;
    bf16_t* W3f  = bp;  bp += 65536;
    bf16_t* W4f  = bp;  bp += 65536;

    hipMemsetAsync(stats, 0, 192 * sizeof(float), stream);
    hipMemsetAsync(xg, 0, 512 * 256 * sizeof(float), stream);

    // grid MUST cover all 360,264 work items (ceil -> 1408 blocks); 1344 was the round-4 bug
    prep_weights<<<1408, 256, 0, stream>>>(gw1, gw2, gw3, gw4, fw1, fw2, c1w, c2w, c3w, c4w,
                                           W1f, W2f, W3f, W4f, fw1T, fw2T,
                                           wT1, wT2, wT3, wT4);

    conv1_bn<<<1024, 256, 0, stream>>>(img, wT1, c1b, y1, stats + 0);

    conv24_bn<38, 38, 19, 19, 5, 2><<<2048, 256, 0, stream>>>(
        y1, wT2, c2b, stats + 0, bn1g, bn1b, 1.f / (512.f * 1444.f),
        y2, stats + 48, 4);

    conv24_bn<19, 19, 10, 10, 10, 2><<<512, 256, 0, stream>>>(
        y2, wT3, c3b, stats + 48, bn2g, bn2b, 1.f / (512.f * 361.f),
        y3, stats + 96, 1);

    conv24_bn<10, 10, 5, 5, 5, 1><<<512, 256, 0, stream>>>(
        y3, wT4, c4b, stats + 96, bn3g, bn3b, 1.f / (512.f * 100.f),
        y4, stats + 144, 1);

    build_features<<<50, 256, 0, stream>>>(y4, stats + 144, bn4g, bn4b, qst, xf26, qstb);

    g_mlp<<<512 * GT_PER_B, 256, 0, stream>>>(xf26, qstb, W1f, W2f, W3f, W4f,
                                              gb1, gb2, gb3, gb4, xg);

    f_mlp<<<512, 256, 0, stream>>>(xg, fw1T, fb1, fw2T, fb2, fw3, fb3, (float*)d_out);
}